// Round 21
// baseline (129.050 us; speedup 1.0000x reference)
//
#include <hip/hip_runtime.h>
#include <stdint.h>

typedef unsigned short u16;
typedef unsigned int   u32;
typedef unsigned char  u8;
typedef __attribute__((ext_vector_type(4))) float f32x4;
typedef __attribute__((ext_vector_type(8))) __bf16 bf16x8;
typedef __attribute__((ext_vector_type(2))) unsigned int u32x2;
typedef __attribute__((ext_vector_type(4))) unsigned int u32x4;

#define MFMA16(a, b, c) __builtin_amdgcn_mfma_f32_16x16x32_bf16((a), (b), (c), 0, 0, 0)

__device__ __forceinline__ u16 f2bf(float f) {
  u32 u = __float_as_uint(f);
  return (u16)((u + 0x7fffu + ((u >> 16) & 1u)) >> 16);  // RNE
}

__device__ __forceinline__ void gl_lds16(const void* g, void* l) {
  __builtin_amdgcn_global_load_lds((const __attribute__((address_space(1))) u32*)g,
                                   (__attribute__((address_space(3))) u32*)l, 16, 0, 0);
}

__device__ __forceinline__ u32 cvtpk(float a, float b) {
  u32 r;
  asm("v_cvt_pk_bf16_f32 %0, %1, %2" : "=v"(r) : "v"(a), "v"(b));
  return r;
}

__device__ __forceinline__ float exp2_hw(float x) {  // v_exp_f32 = 2^x
  float r;
  asm("v_exp_f32 %0, %1" : "=v"(r) : "v"(x));
  return r;
}

__device__ __forceinline__ void plswap32(u32& x, u32& y) {
  u32x2 r = __builtin_amdgcn_permlane32_swap(x, y, false, false);
  x = r.x; y = r.y;
}
__device__ __forceinline__ void plswap16(u32& x, u32& y) {
  u32x2 r = __builtin_amdgcn_permlane16_swap(x, y, false, false);
  x = r.x; y = r.y;
}

// ---------------- f32 -> bf16 cvt: one input+output stream per block ----------------
__global__ void __launch_bounds__(256) cvt_kernel(const float4* __restrict__ Q, const float4* __restrict__ K,
                                                  const float4* __restrict__ V, const float4* __restrict__ Wq,
                                                  const float4* __restrict__ Wk, const float4* __restrict__ Wv,
                                                  const float4* __restrict__ Wo, ushort4* __restrict__ oQ,
                                                  ushort4* __restrict__ oK, ushort4* __restrict__ oV,
                                                  ushort4* __restrict__ oWq, ushort4* __restrict__ oWk,
                                                  ushort4* __restrict__ oWv, ushort4* __restrict__ oWo) {
  const int cb = blockIdx.x;
  const float4* src;
  ushort4* dst;
  int base;
  if (cb < 1024)      { src = Q;  dst = oQ;  base = cb; }
  else if (cb < 2048) { src = K;  dst = oK;  base = cb - 1024; }
  else if (cb < 3072) { src = V;  dst = oV;  base = cb - 2048; }
  else if (cb < 3328) { src = Wq; dst = oWq; base = cb - 3072; }
  else if (cb < 3584) { src = Wk; dst = oWk; base = cb - 3328; }
  else if (cb < 3840) { src = Wv; dst = oWv; base = cb - 3584; }
  else                { src = Wo; dst = oWo; base = cb - 3840; }
  const int i0 = base * 1024 + threadIdx.x;
#pragma unroll
  for (int u = 0; u < 4; u++) {
    const int i = i0 + u * 256;
    float4 v = src[i];
    dst[i] = make_ushort4(f2bf(v.x), f2bf(v.y), f2bf(v.z), f2bf(v.w));
  }
}

// ---------------- mask pack (standalone, solo-optimal ~16 us) ----------------
// bits: 0=token 1=stmt 2=df 3=cf 4=mask!=0 5=token|!mask 6=stmt|!mask 7=!mask
__device__ __forceinline__ u32 pbit(float t, float s, float d, float c, int m) {
  const u32 nm = (m == 0) ? 1u : 0u;
  u32 r = (t != 0.0f ? 1u : 0u) | (s != 0.0f ? 2u : 0u) | (d != 0.0f ? 4u : 0u) |
          (c != 0.0f ? 8u : 0u) | ((1u - nm) << 4);
  r |= (((t != 0.0f ? 1u : 0u) | nm) << 5) | (((s != 0.0f ? 1u : 0u) | nm) << 6) | (nm << 7);
  return r;
}

__global__ void __launch_bounds__(256) pack_kernel(const float4* __restrict__ tok, const float4* __restrict__ st,
                                                   const float4* __restrict__ df, const float4* __restrict__ cf,
                                                   const int4* __restrict__ msk, u32* __restrict__ pko) {
  const int i = blockIdx.x * 256 + threadIdx.x;  // float4 index over (b,q,k4)
  const int b = i >> 18, rem = i & 262143, q = rem >> 8, k4 = rem & 255;
  const int t = k4 >> 4, nk = (k4 >> 2) & 3, lg = k4 & 3;
  const u32 widx = ((u32)(b * 64 + (q >> 4)) * 16 + t) * 256 + (q & 15) * 16 + lg * 4 + nk;
  float4 vt = tok[i], vs = st[i], vd = df[i], vc = cf[i];
  int4 vm = msk[i];
  u32 b0 = pbit(vt.x, vs.x, vd.x, vc.x, vm.x);
  u32 b1 = pbit(vt.y, vs.y, vd.y, vc.y, vm.y);
  u32 b2 = pbit(vt.z, vs.z, vd.z, vc.z, vm.z);
  u32 b3 = pbit(vt.w, vs.w, vd.w, vc.w, vm.w);
  pko[widx] = b0 | (b1 << 8) | (b2 << 16) | (b3 << 24);
}

// ---------------- batched QKV projection GEMM: 128x128 tile, double-buffered, single barrier/iter ----------------
__global__ void __launch_bounds__(256) gemm_qkv(const u16* __restrict__ Abase, const u16* __restrict__ Wbase,
                                                const float* __restrict__ bq, const float* __restrict__ bk,
                                                const float* __restrict__ bv, u16* __restrict__ Obase) {
  __shared__ u16 smA[2][4096];
  __shared__ u16 smB[2][4096];
  const int fb = blockIdx.x;
  const int lid = (fb & 7) * 96 + (fb >> 3);
  const int z = lid >> 8;
  const int m0 = ((lid & 255) >> 3) * 128;
  const int n0 = (lid & 7) * 128;
  const u16* A = Abase + (size_t)z * 4194304;
  const u16* W = Wbase + (size_t)z * 1048576;
  const float* bias = (z == 0) ? bq : (z == 1) ? bk : bv;
  u16* Out = Obase + (size_t)z * 4194304;
  const int t = threadIdx.x;
  const int w = t >> 6, l = t & 63;
  const int l15 = l & 15, lg = l >> 4;
  const int wr = w >> 1, wc = w & 1;
  f32x4 acc[4][4] = {};
  const int srow = w * 16 + (l >> 2);
  const int scol_src = (((l & 3) ^ ((l >> 2) & 3))) * 8;  // swizzled global source chunk
  const int scol_dst = (l & 3) * 8;                        // linear gl_lds dest
  const u16* Ab = A + (size_t)(m0 + srow) * 1024 + scol_src;
  const u16* Wb = W + (size_t)(n0 + srow) * 1024 + scol_src;
  const int soff = srow * 32 + scol_dst;
  const int c0g = (lg ^ (l15 & 3)) * 8;  // swizzled read chunk

  gl_lds16(Ab, &smA[0][soff]);
  gl_lds16(Ab + (size_t)64 * 1024, &smA[0][soff + 64 * 32]);
  gl_lds16(Wb, &smB[0][soff]);
  gl_lds16(Wb + (size_t)64 * 1024, &smB[0][soff + 64 * 32]);

  for (int it = 0; it < 32; it++) {
    __syncthreads();  // drains stage(it); all waves done with buf[(it+1)&1]
    if (it < 31) {
      const int kk = (it + 1) * 32;
      const int nb = (it + 1) & 1;
      gl_lds16(Ab + kk, &smA[nb][soff]);
      gl_lds16(Ab + kk + (size_t)64 * 1024, &smA[nb][soff + 64 * 32]);
      gl_lds16(Wb + kk, &smB[nb][soff]);
      gl_lds16(Wb + kk + (size_t)64 * 1024, &smB[nb][soff + 64 * 32]);
    }
    const u16* bA = smA[it & 1];
    const u16* bB = smB[it & 1];
    bf16x8 af[4], bv_[4];
#pragma unroll
    for (int i = 0; i < 4; i++) af[i] = *(const bf16x8*)(bA + (wr * 64 + i * 16 + l15) * 32 + c0g);
#pragma unroll
    for (int i = 0; i < 4; i++) bv_[i] = *(const bf16x8*)(bB + (wc * 64 + i * 16 + l15) * 32 + c0g);
#pragma unroll
    for (int i = 0; i < 4; i++)
#pragma unroll
      for (int j = 0; j < 4; j++) acc[i][j] = MFMA16(af[i], bv_[j], acc[i][j]);
  }
#pragma unroll
  for (int j = 0; j < 4; j++) {
    const int n = n0 + wc * 64 + j * 16 + l15;
    const float bvj = bias[n];
#pragma unroll
    for (int i = 0; i < 4; i++) {
      const int mbase = m0 + wr * 64 + i * 16 + lg * 4;
      if (z < 2) {
#pragma unroll
        for (int r = 0; r < 4; r++) {
          const int m = mbase + r;
          Out[((size_t)((m >> 10) * 16 + (n >> 6)) << 16) + (size_t)(m & 1023) * 64 + (n & 63)] =
              f2bf(acc[i][j][r] + bvj);
        }
      } else {
        size_t off = ((size_t)((mbase >> 10) * 16 + (n >> 6)) << 16) + (size_t)(n & 63) * 1024 + (mbase & 1023);
        *(ushort4*)(Out + off) = make_ushort4(f2bf(acc[i][j][0] + bvj), f2bf(acc[i][j][1] + bvj),
                                              f2bf(acc[i][j][2] + bvj), f2bf(acc[i][j][3] + bvj));
      }
    }
  }
}

// ---------------- output projection GEMM: 128x128 tile, f32 out ----------------
__global__ void __launch_bounds__(256) gemm_out(const u16* __restrict__ A, const u16* __restrict__ W,
                                                const float* __restrict__ bias, float* __restrict__ Out) {
  __shared__ u16 smA[2][4096];
  __shared__ u16 smB[2][4096];
  const int fb = blockIdx.x;
  const int lid = (fb & 7) * 32 + (fb >> 3);
  const int m0 = (lid >> 3) * 128;
  const int n0 = (lid & 7) * 128;
  const int t = threadIdx.x;
  const int w = t >> 6, l = t & 63;
  const int l15 = l & 15, lg = l >> 4;
  const int wr = w >> 1, wc = w & 1;
  f32x4 acc[4][4] = {};
  const int srow = w * 16 + (l >> 2);
  const int scol_src = (((l & 3) ^ ((l >> 2) & 3))) * 8;
  const int scol_dst = (l & 3) * 8;
  const u16* Ab = A + (size_t)(m0 + srow) * 1024 + scol_src;
  const u16* Wb = W + (size_t)(n0 + srow) * 1024 + scol_src;
  const int soff = srow * 32 + scol_dst;
  const int c0g = (lg ^ (l15 & 3)) * 8;

  gl_lds16(Ab, &smA[0][soff]);
  gl_lds16(Ab + (size_t)64 * 1024, &smA[0][soff + 64 * 32]);
  gl_lds16(Wb, &smB[0][soff]);
  gl_lds16(Wb + (size_t)64 * 1024, &smB[0][soff + 64 * 32]);

  for (int it = 0; it < 32; it++) {
    __syncthreads();
    if (it < 31) {
      const int kk = (it + 1) * 32;
      const int nb = (it + 1) & 1;
      gl_lds16(Ab + kk, &smA[nb][soff]);
      gl_lds16(Ab + kk + (size_t)64 * 1024, &smA[nb][soff + 64 * 32]);
      gl_lds16(Wb + kk, &smB[nb][soff]);
      gl_lds16(Wb + kk + (size_t)64 * 1024, &smB[nb][soff + 64 * 32]);
    }
    const u16* bA = smA[it & 1];
    const u16* bB = smB[it & 1];
    bf16x8 af[4], bv_[4];
#pragma unroll
    for (int i = 0; i < 4; i++) af[i] = *(const bf16x8*)(bA + (wr * 64 + i * 16 + l15) * 32 + c0g);
#pragma unroll
    for (int i = 0; i < 4; i++) bv_[i] = *(const bf16x8*)(bB + (wc * 64 + i * 16 + l15) * 32 + c0g);
#pragma unroll
    for (int i = 0; i < 4; i++)
#pragma unroll
      for (int j = 0; j < 4; j++) acc[i][j] = MFMA16(af[i], bv_[j], acc[i][j]);
  }
#pragma unroll
  for (int j = 0; j < 4; j++) {
    const int n = n0 + wc * 64 + j * 16 + l15;
    const float bvj = bias[n];
#pragma unroll
    for (int i = 0; i < 4; i++) {
      const int mbase = m0 + wr * 64 + i * 16 + lg * 4;
#pragma unroll
      for (int r = 0; r < 4; r++) Out[(size_t)(mbase + r) * 1024 + n] = acc[i][j][r] + bvj;
    }
  }
}

// ---------------- flash attention: 8-wave blocks (128 q), shared K/V LDS, fixed-max softmax ----------------
__global__ void __launch_bounds__(512) attn_kernel(const u16* __restrict__ Qp, const u16* __restrict__ Kp,
                                                   const u16* __restrict__ Vt, const u8* __restrict__ pack,
                                                   u16* __restrict__ ctx) {
  __shared__ u16 smK[2][4096];
  __shared__ u16 smV[2][4096];
  const float SCL  = 0.18033688011112042f;  // 0.125 * log2(e)
  const float FMX  = 32.0f;                 // fixed softmax max (log2 domain)
  const int tid = threadIdx.x;
  const int w = tid >> 6, l = tid & 63;     // w = 0..7
  const int l15 = l & 15, lg = l >> 4;
  const int f = blockIdx.x;
  const int swz = (f & 7) * 64 + (f >> 3);  // bijective XCD swizzle (512 = 8*64)
  const int bh = swz >> 3, bx = swz & 7;
  const int b = bh >> 4, h = bh & 15;
  const int q0 = bx * 128 + w * 16;
  const bool enh = (h >= 8 && h < 12);
  const u32 kbit = (h < 4) ? 0x20u : (h < 8) ? 0x40u : 0x80u;
  const u32 ebit = (h < 10) ? 0x04u : 0x08u;
  const u32 kb_[4] = {kbit, kbit << 8, kbit << 16, kbit << 24};
  const u32 eb_[4] = {ebit, ebit << 8, ebit << 16, ebit << 24};
  const size_t hb = (size_t)bh << 16;
  const u32x4 onesw = {0x3F803F80u, 0x3F803F80u, 0x3F803F80u, 0x3F803F80u};
  const bf16x8 ones_frag = __builtin_bit_cast(bf16x8, onesw);

  bf16x8 qf[2];
#pragma unroll
  for (int ks = 0; ks < 2; ks++)
    qf[ks] = *(const bf16x8*)(Qp + hb + (size_t)(q0 + l15) * 64 + ks * 32 + lg * 8);

  const int srow = w * 8 + (l >> 3);
  const int schunk = (l & 7) ^ (l >> 3);
  const u16* Ksrc = Kp + hb + (size_t)srow * 64 + schunk * 8;
  const u16* Vsrc = Vt + hb + (size_t)srow * 1024 + schunk * 8;
  const int c0 = (lg ^ (l15 & 7)) * 8;
  const u8* pkq = pack + ((size_t)((b * 64 + bx * 8 + w) * 16)) * 1024 + (l15 * 4 + lg) * 16;

  gl_lds16(Ksrc, &smK[0][w * 512]);
  gl_lds16(Vsrc, &smV[0][w * 512]);
  uint4 pk_next = *(const uint4*)(pkq);

  f32x4 octx[4] = {};
  f32x4 osum = {};

  for (int t = 0; t < 16; t++) {
    __syncthreads();
    const uint4 pkc = pk_next;
    if (t < 15) {
      const int kb = (t + 1) * 64;
      const int nb = (t + 1) & 1;
      gl_lds16(Ksrc + (size_t)kb * 64, &smK[nb][w * 512]);
      gl_lds16(Vsrc + kb, &smV[nb][w * 512]);
      pk_next = *(const uint4*)(pkq + (t + 1) * 1024);
    }
    const u16* bK = smK[t & 1];
    const u16* bV = smV[t & 1];
    f32x4 sc[4];
    __builtin_amdgcn_s_setprio(1);
#pragma unroll
    for (int nk = 0; nk < 4; nk++) {
      const u16* kr = bK + (nk * 16 + l15) * 64;
      bf16x8 kf0 = *(const bf16x8*)(kr + c0);
      bf16x8 kf1 = *(const bf16x8*)(kr + (c0 ^ 32));
      f32x4 z = {0.0f, 0.0f, 0.0f, 0.0f};
      z = MFMA16(kf0, qf[0], z);
      z = MFMA16(kf1, qf[1], z);
      sc[nk] = z;
    }
    __builtin_amdgcn_s_setprio(0);
    const u32 pkw[4] = {pkc.x, pkc.y, pkc.z, pkc.w};
#pragma unroll
    for (int nk = 0; nk < 4; nk++)
#pragma unroll
      for (int r = 0; r < 4; r++) {
        float s;
        if (enh) {
          float tt = sc[nk][r] * SCL;
          tt = (pkw[nk] & eb_[r]) ? __builtin_fmaf(fabsf(tt), 5.0f, tt) : tt;
          s = tt - FMX;
        } else {
          s = __builtin_fmaf(sc[nk][r], SCL, -FMX);
        }
        float p = exp2_hw(s);
        p = (pkw[nk] & kb_[r]) ? 0.0f : p;
        sc[nk][r] = p;
      }
    __builtin_amdgcn_s_setprio(1);
#pragma unroll
    for (int kk = 0; kk < 2; kk++) {
      u32 a0 = cvtpk(sc[2 * kk][0], sc[2 * kk][1]);
      u32 a1 = cvtpk(sc[2 * kk][2], sc[2 * kk][3]);
      u32 b0 = cvtpk(sc[2 * kk + 1][0], sc[2 * kk + 1][1]);
      u32 b1 = cvtpk(sc[2 * kk + 1][2], sc[2 * kk + 1][3]);
      plswap32(a0, b0);
      plswap32(a1, b1);
      plswap16(a0, b0);
      plswap16(a1, b1);
      u32x4 wv = {a0, a1, b0, b1};
      bf16x8 pfrag = __builtin_bit_cast(bf16x8, wv);
      osum = MFMA16(ones_frag, pfrag, osum);
#pragma unroll
      for (int nd = 0; nd < 4; nd++) {
        bf16x8 vf = *(const bf16x8*)(bV + (nd * 16 + l15) * 64 + (c0 ^ (kk * 32)));
        octx[nd] = MFMA16(vf, pfrag, octx[nd]);
      }
    }
    __builtin_amdgcn_s_setprio(0);
  }
  const float inv = 1.0f / fmaxf(osum[0], 1e-35f);
  u16* cb = ctx + (size_t)b * 1048576 + (size_t)(q0 + l15) * 1024 + h * 64 + lg * 4;
#pragma unroll
  for (int nd = 0; nd < 4; nd++) {
    *(ushort4*)(cb + nd * 16) = make_ushort4(f2bf(octx[nd][0] * inv), f2bf(octx[nd][1] * inv),
                                             f2bf(octx[nd][2] * inv), f2bf(octx[nd][3] * inv));
  }
}

extern "C" void kernel_launch(void* const* d_in, const int* in_sizes, int n_in,
                              void* d_out, int out_size, void* d_ws, size_t ws_size,
                              hipStream_t stream) {
  (void)in_sizes; (void)n_in; (void)out_size; (void)ws_size;
  const float* Q  = (const float*)d_in[0];
  const float* K  = (const float*)d_in[1];
  const float* V  = (const float*)d_in[2];
  const float* tok = (const float*)d_in[3];
  const float* st  = (const float*)d_in[4];
  const float* df  = (const float*)d_in[5];
  const float* cf  = (const float*)d_in[6];
  const int*   msk = (const int*)d_in[8];
  const float* Wq = (const float*)d_in[9];
  const float* bq = (const float*)d_in[10];
  const float* Wk = (const float*)d_in[11];
  const float* bk = (const float*)d_in[12];
  const float* Wv = (const float*)d_in[13];
  const float* bv = (const float*)d_in[14];
  const float* Wo = (const float*)d_in[15];
  const float* bo = (const float*)d_in[16];

  char* ws = (char*)d_ws;
  const size_t MB = 1ull << 20;
  u16* Qbf = (u16*)(ws);            // 3 x 8 MB (Q,K,V bf16)
  u16* Wqb = (u16*)(ws + 24 * MB);  // 4 x 2 MB (Wq,Wk,Wv,Wo bf16)
  u8*  pkQ = (u8*)(ws + 32 * MB);   // 4 MB packed masks
  u16* Qh  = (u16*)(ws + 36 * MB);  // 3 x 8 MB (Qh,Kh,VhT)
  u16* ctx = (u16*)(ws + 60 * MB);  // 8 MB
  u16* Kbf = Qbf + 4194304;
  u16* Vbf = Qbf + 8388608;
  u16* Wkb = Wqb + 1048576;
  u16* Wvb = Wqb + 2097152;
  u16* Wob = Wqb + 3145728;

  cvt_kernel<<<4096, 256, 0, stream>>>((const float4*)Q, (const float4*)K, (const float4*)V,
                                       (const float4*)Wq, (const float4*)Wk, (const float4*)Wv, (const float4*)Wo,
                                       (ushort4*)Qbf, (ushort4*)Kbf, (ushort4*)Vbf,
                                       (ushort4*)Wqb, (ushort4*)Wkb, (ushort4*)Wvb, (ushort4*)Wob);
  gemm_qkv<<<768, 256, 0, stream>>>(Qbf, Wqb, bq, bk, bv, Qh);
  pack_kernel<<<4096, 256, 0, stream>>>((const float4*)tok, (const float4*)st, (const float4*)df,
                                        (const float4*)cf, (const int4*)msk, (u32*)pkQ);
  attn_kernel<<<512, 512, 0, stream>>>(Qh, Qh + 4194304, Qh + 8388608, pkQ, ctx);
  gemm_out<<<256, 256, 0, stream>>>(ctx, Wob, bo, (float*)d_out);
}

// Round 22
// 118.851 us; speedup vs baseline: 1.0858x; 1.0858x over previous
//
#include <hip/hip_runtime.h>
#include <stdint.h>

typedef unsigned short u16;
typedef unsigned int   u32;
typedef unsigned char  u8;
typedef __attribute__((ext_vector_type(4))) float f32x4;
typedef __attribute__((ext_vector_type(8))) __bf16 bf16x8;
typedef __attribute__((ext_vector_type(2))) unsigned int u32x2;
typedef __attribute__((ext_vector_type(4))) unsigned int u32x4;

#define MFMA16(a, b, c) __builtin_amdgcn_mfma_f32_16x16x32_bf16((a), (b), (c), 0, 0, 0)

__device__ __forceinline__ u16 f2bf(float f) {
  u32 u = __float_as_uint(f);
  return (u16)((u + 0x7fffu + ((u >> 16) & 1u)) >> 16);  // RNE
}

__device__ __forceinline__ void gl_lds16(const void* g, void* l) {
  __builtin_amdgcn_global_load_lds((const __attribute__((address_space(1))) u32*)g,
                                   (__attribute__((address_space(3))) u32*)l, 16, 0, 0);
}

__device__ __forceinline__ u32 cvtpk(float a, float b) {
  u32 r;
  asm("v_cvt_pk_bf16_f32 %0, %1, %2" : "=v"(r) : "v"(a), "v"(b));
  return r;
}

__device__ __forceinline__ float exp2_hw(float x) {  // v_exp_f32 = 2^x
  float r;
  asm("v_exp_f32 %0, %1" : "=v"(r) : "v"(x));
  return r;
}

__device__ __forceinline__ void plswap32(u32& x, u32& y) {
  u32x2 r = __builtin_amdgcn_permlane32_swap(x, y, false, false);
  x = r.x; y = r.y;
}
__device__ __forceinline__ void plswap16(u32& x, u32& y) {
  u32x2 r = __builtin_amdgcn_permlane16_swap(x, y, false, false);
  x = r.x; y = r.y;
}

// ---------------- f32 -> bf16 cvt: one input+output stream per block ----------------
__global__ void __launch_bounds__(256) cvt_kernel(const float4* __restrict__ Q, const float4* __restrict__ K,
                                                  const float4* __restrict__ V, const float4* __restrict__ Wq,
                                                  const float4* __restrict__ Wk, const float4* __restrict__ Wv,
                                                  const float4* __restrict__ Wo, ushort4* __restrict__ oQ,
                                                  ushort4* __restrict__ oK, ushort4* __restrict__ oV,
                                                  ushort4* __restrict__ oWq, ushort4* __restrict__ oWk,
                                                  ushort4* __restrict__ oWv, ushort4* __restrict__ oWo) {
  const int cb = blockIdx.x;
  const float4* src;
  ushort4* dst;
  int base;
  if (cb < 1024)      { src = Q;  dst = oQ;  base = cb; }
  else if (cb < 2048) { src = K;  dst = oK;  base = cb - 1024; }
  else if (cb < 3072) { src = V;  dst = oV;  base = cb - 2048; }
  else if (cb < 3328) { src = Wq; dst = oWq; base = cb - 3072; }
  else if (cb < 3584) { src = Wk; dst = oWk; base = cb - 3328; }
  else if (cb < 3840) { src = Wv; dst = oWv; base = cb - 3584; }
  else                { src = Wo; dst = oWo; base = cb - 3840; }
  const int i0 = base * 1024 + threadIdx.x;
#pragma unroll
  for (int u = 0; u < 4; u++) {
    const int i = i0 + u * 256;
    float4 v = src[i];
    dst[i] = make_ushort4(f2bf(v.x), f2bf(v.y), f2bf(v.z), f2bf(v.w));
  }
}

// ---------------- fused launch: blocks [0,768) = QKV GEMM, [768,4864) = mask pack ----------------
// Pack (pure streaming) co-resides with GEMM blocks and soaks idle HBM/L3 bandwidth while the
// GEMM computes; its output is only consumed by the NEXT launch (attn). Measured win vs separate.
__device__ __forceinline__ u32 pbit(float t, float s, float d, float c, int m) {
  const u32 nm = (m == 0) ? 1u : 0u;
  u32 r = (t != 0.0f ? 1u : 0u) | (s != 0.0f ? 2u : 0u) | (d != 0.0f ? 4u : 0u) |
          (c != 0.0f ? 8u : 0u) | ((1u - nm) << 4);
  r |= (((t != 0.0f ? 1u : 0u) | nm) << 5) | (((s != 0.0f ? 1u : 0u) | nm) << 6) | (nm << 7);
  return r;
}

__global__ void __launch_bounds__(256) gemm_qkv_pack(
    const u16* __restrict__ Abase, const u16* __restrict__ Wbase, const float* __restrict__ bq,
    const float* __restrict__ bk, const float* __restrict__ bv, u16* __restrict__ Obase,
    const float4* __restrict__ tok, const float4* __restrict__ st, const float4* __restrict__ df,
    const float4* __restrict__ cf, const int4* __restrict__ msk, u32* __restrict__ pko) {
  __shared__ u16 smA[2][4096];
  __shared__ u16 smB[2][4096];
  const int fb = blockIdx.x;
  if (fb >= 768) {  // ---- pack path ----
    const int i = (fb - 768) * 256 + threadIdx.x;  // float4 index over (b,q,k4)
    const int b = i >> 18, rem = i & 262143, q = rem >> 8, k4 = rem & 255;
    const int t = k4 >> 4, nk = (k4 >> 2) & 3, lg = k4 & 3;
    const u32 widx = ((u32)(b * 64 + (q >> 4)) * 16 + t) * 256 + (q & 15) * 16 + lg * 4 + nk;
    float4 vt = tok[i], vs = st[i], vd = df[i], vc = cf[i];
    int4 vm = msk[i];
    u32 b0 = pbit(vt.x, vs.x, vd.x, vc.x, vm.x);
    u32 b1 = pbit(vt.y, vs.y, vd.y, vc.y, vm.y);
    u32 b2 = pbit(vt.z, vs.z, vd.z, vc.z, vm.z);
    u32 b3 = pbit(vt.w, vs.w, vd.w, vc.w, vm.w);
    pko[widx] = b0 | (b1 << 8) | (b2 << 16) | (b3 << 24);
    return;
  }
  // ---- GEMM path (measured-best 128x128 double-buffered structure) ----
  const int lid = (fb & 7) * 96 + (fb >> 3);
  const int z = lid >> 8;
  const int m0 = ((lid & 255) >> 3) * 128;
  const int n0 = (lid & 7) * 128;
  const u16* A = Abase + (size_t)z * 4194304;
  const u16* W = Wbase + (size_t)z * 1048576;
  const float* bias = (z == 0) ? bq : (z == 1) ? bk : bv;
  u16* Out = Obase + (size_t)z * 4194304;
  const int t = threadIdx.x;
  const int w = t >> 6, l = t & 63;
  const int l15 = l & 15, lg = l >> 4;
  const int wr = w >> 1, wc = w & 1;
  f32x4 acc[4][4] = {};
  const int srow = w * 16 + (l >> 2);
  const int scol_src = (((l & 3) ^ ((l >> 2) & 3))) * 8;  // swizzled global source chunk
  const int scol_dst = (l & 3) * 8;                        // linear gl_lds dest
  const u16* Ab = A + (size_t)(m0 + srow) * 1024 + scol_src;
  const u16* Wb = W + (size_t)(n0 + srow) * 1024 + scol_src;
  const int soff = srow * 32 + scol_dst;
  const int c0g = (lg ^ (l15 & 3)) * 8;  // swizzled read chunk

  gl_lds16(Ab, &smA[0][soff]);
  gl_lds16(Ab + (size_t)64 * 1024, &smA[0][soff + 64 * 32]);
  gl_lds16(Wb, &smB[0][soff]);
  gl_lds16(Wb + (size_t)64 * 1024, &smB[0][soff + 64 * 32]);

  for (int it = 0; it < 32; it++) {
    __syncthreads();  // drains stage(it); all waves done with buf[(it+1)&1]
    if (it < 31) {
      const int kk = (it + 1) * 32;
      const int nb = (it + 1) & 1;
      gl_lds16(Ab + kk, &smA[nb][soff]);
      gl_lds16(Ab + kk + (size_t)64 * 1024, &smA[nb][soff + 64 * 32]);
      gl_lds16(Wb + kk, &smB[nb][soff]);
      gl_lds16(Wb + kk + (size_t)64 * 1024, &smB[nb][soff + 64 * 32]);
    }
    const u16* bA = smA[it & 1];
    const u16* bB = smB[it & 1];
    bf16x8 af[4], bv_[4];
#pragma unroll
    for (int i = 0; i < 4; i++) af[i] = *(const bf16x8*)(bA + (wr * 64 + i * 16 + l15) * 32 + c0g);
#pragma unroll
    for (int i = 0; i < 4; i++) bv_[i] = *(const bf16x8*)(bB + (wc * 64 + i * 16 + l15) * 32 + c0g);
#pragma unroll
    for (int i = 0; i < 4; i++)
#pragma unroll
      for (int j = 0; j < 4; j++) acc[i][j] = MFMA16(af[i], bv_[j], acc[i][j]);
  }
#pragma unroll
  for (int j = 0; j < 4; j++) {
    const int n = n0 + wc * 64 + j * 16 + l15;
    const float bvj = bias[n];
#pragma unroll
    for (int i = 0; i < 4; i++) {
      const int mbase = m0 + wr * 64 + i * 16 + lg * 4;
      if (z < 2) {
#pragma unroll
        for (int r = 0; r < 4; r++) {
          const int m = mbase + r;
          Out[((size_t)((m >> 10) * 16 + (n >> 6)) << 16) + (size_t)(m & 1023) * 64 + (n & 63)] =
              f2bf(acc[i][j][r] + bvj);
        }
      } else {
        size_t off = ((size_t)((mbase >> 10) * 16 + (n >> 6)) << 16) + (size_t)(n & 63) * 1024 + (mbase & 1023);
        *(ushort4*)(Out + off) = make_ushort4(f2bf(acc[i][j][0] + bvj), f2bf(acc[i][j][1] + bvj),
                                              f2bf(acc[i][j][2] + bvj), f2bf(acc[i][j][3] + bvj));
      }
    }
  }
}

// ---------------- output projection GEMM: 128x128 tile, f32 out ----------------
__global__ void __launch_bounds__(256) gemm_out(const u16* __restrict__ A, const u16* __restrict__ W,
                                                const float* __restrict__ bias, float* __restrict__ Out) {
  __shared__ u16 smA[2][4096];
  __shared__ u16 smB[2][4096];
  const int fb = blockIdx.x;
  const int lid = (fb & 7) * 32 + (fb >> 3);
  const int m0 = (lid >> 3) * 128;
  const int n0 = (lid & 7) * 128;
  const int t = threadIdx.x;
  const int w = t >> 6, l = t & 63;
  const int l15 = l & 15, lg = l >> 4;
  const int wr = w >> 1, wc = w & 1;
  f32x4 acc[4][4] = {};
  const int srow = w * 16 + (l >> 2);
  const int scol_src = (((l & 3) ^ ((l >> 2) & 3))) * 8;
  const int scol_dst = (l & 3) * 8;
  const u16* Ab = A + (size_t)(m0 + srow) * 1024 + scol_src;
  const u16* Wb = W + (size_t)(n0 + srow) * 1024 + scol_src;
  const int soff = srow * 32 + scol_dst;
  const int c0g = (lg ^ (l15 & 3)) * 8;

  gl_lds16(Ab, &smA[0][soff]);
  gl_lds16(Ab + (size_t)64 * 1024, &smA[0][soff + 64 * 32]);
  gl_lds16(Wb, &smB[0][soff]);
  gl_lds16(Wb + (size_t)64 * 1024, &smB[0][soff + 64 * 32]);

  for (int it = 0; it < 32; it++) {
    __syncthreads();
    if (it < 31) {
      const int kk = (it + 1) * 32;
      const int nb = (it + 1) & 1;
      gl_lds16(Ab + kk, &smA[nb][soff]);
      gl_lds16(Ab + kk + (size_t)64 * 1024, &smA[nb][soff + 64 * 32]);
      gl_lds16(Wb + kk, &smB[nb][soff]);
      gl_lds16(Wb + kk + (size_t)64 * 1024, &smB[nb][soff + 64 * 32]);
    }
    const u16* bA = smA[it & 1];
    const u16* bB = smB[it & 1];
    bf16x8 af[4], bv_[4];
#pragma unroll
    for (int i = 0; i < 4; i++) af[i] = *(const bf16x8*)(bA + (wr * 64 + i * 16 + l15) * 32 + c0g);
#pragma unroll
    for (int i = 0; i < 4; i++) bv_[i] = *(const bf16x8*)(bB + (wc * 64 + i * 16 + l15) * 32 + c0g);
#pragma unroll
    for (int i = 0; i < 4; i++)
#pragma unroll
      for (int j = 0; j < 4; j++) acc[i][j] = MFMA16(af[i], bv_[j], acc[i][j]);
  }
#pragma unroll
  for (int j = 0; j < 4; j++) {
    const int n = n0 + wc * 64 + j * 16 + l15;
    const float bvj = bias[n];
#pragma unroll
    for (int i = 0; i < 4; i++) {
      const int mbase = m0 + wr * 64 + i * 16 + lg * 4;
#pragma unroll
      for (int r = 0; r < 4; r++) Out[(size_t)(mbase + r) * 1024 + n] = acc[i][j][r] + bvj;
    }
  }
}

// ---------------- flash attention: 8-wave blocks (128 q), shared K/V LDS, fixed-max softmax ----------------
__global__ void __launch_bounds__(512) attn_kernel(const u16* __restrict__ Qp, const u16* __restrict__ Kp,
                                                   const u16* __restrict__ Vt, const u8* __restrict__ pack,
                                                   u16* __restrict__ ctx) {
  __shared__ u16 smK[2][4096];
  __shared__ u16 smV[2][4096];
  const float SCL  = 0.18033688011112042f;  // 0.125 * log2(e)
  const float FMX  = 32.0f;                 // fixed softmax max (log2 domain)
  const int tid = threadIdx.x;
  const int w = tid >> 6, l = tid & 63;     // w = 0..7
  const int l15 = l & 15, lg = l >> 4;
  const int f = blockIdx.x;
  const int swz = (f & 7) * 64 + (f >> 3);  // bijective XCD swizzle (512 = 8*64)
  const int bh = swz >> 3, bx = swz & 7;
  const int b = bh >> 4, h = bh & 15;
  const int q0 = bx * 128 + w * 16;
  const bool enh = (h >= 8 && h < 12);
  const u32 kbit = (h < 4) ? 0x20u : (h < 8) ? 0x40u : 0x80u;
  const u32 ebit = (h < 10) ? 0x04u : 0x08u;
  const u32 kb_[4] = {kbit, kbit << 8, kbit << 16, kbit << 24};
  const u32 eb_[4] = {ebit, ebit << 8, ebit << 16, ebit << 24};
  const size_t hb = (size_t)bh << 16;
  const u32x4 onesw = {0x3F803F80u, 0x3F803F80u, 0x3F803F80u, 0x3F803F80u};
  const bf16x8 ones_frag = __builtin_bit_cast(bf16x8, onesw);

  bf16x8 qf[2];
#pragma unroll
  for (int ks = 0; ks < 2; ks++)
    qf[ks] = *(const bf16x8*)(Qp + hb + (size_t)(q0 + l15) * 64 + ks * 32 + lg * 8);

  const int srow = w * 8 + (l >> 3);
  const int schunk = (l & 7) ^ (l >> 3);
  const u16* Ksrc = Kp + hb + (size_t)srow * 64 + schunk * 8;
  const u16* Vsrc = Vt + hb + (size_t)srow * 1024 + schunk * 8;
  const int c0 = (lg ^ (l15 & 7)) * 8;
  const u8* pkq = pack + ((size_t)((b * 64 + bx * 8 + w) * 16)) * 1024 + (l15 * 4 + lg) * 16;

  gl_lds16(Ksrc, &smK[0][w * 512]);
  gl_lds16(Vsrc, &smV[0][w * 512]);
  uint4 pk_next = *(const uint4*)(pkq);

  f32x4 octx[4] = {};
  f32x4 osum = {};

  for (int t = 0; t < 16; t++) {
    __syncthreads();
    const uint4 pkc = pk_next;
    if (t < 15) {
      const int kb = (t + 1) * 64;
      const int nb = (t + 1) & 1;
      gl_lds16(Ksrc + (size_t)kb * 64, &smK[nb][w * 512]);
      gl_lds16(Vsrc + kb, &smV[nb][w * 512]);
      pk_next = *(const uint4*)(pkq + (t + 1) * 1024);
    }
    const u16* bK = smK[t & 1];
    const u16* bV = smV[t & 1];
    f32x4 sc[4];
    __builtin_amdgcn_s_setprio(1);
#pragma unroll
    for (int nk = 0; nk < 4; nk++) {
      const u16* kr = bK + (nk * 16 + l15) * 64;
      bf16x8 kf0 = *(const bf16x8*)(kr + c0);
      bf16x8 kf1 = *(const bf16x8*)(kr + (c0 ^ 32));
      f32x4 z = {0.0f, 0.0f, 0.0f, 0.0f};
      z = MFMA16(kf0, qf[0], z);
      z = MFMA16(kf1, qf[1], z);
      sc[nk] = z;
    }
    __builtin_amdgcn_s_setprio(0);
    const u32 pkw[4] = {pkc.x, pkc.y, pkc.z, pkc.w};
#pragma unroll
    for (int nk = 0; nk < 4; nk++)
#pragma unroll
      for (int r = 0; r < 4; r++) {
        float s;
        if (enh) {
          float tt = sc[nk][r] * SCL;
          tt = (pkw[nk] & eb_[r]) ? __builtin_fmaf(fabsf(tt), 5.0f, tt) : tt;
          s = tt - FMX;
        } else {
          s = __builtin_fmaf(sc[nk][r], SCL, -FMX);
        }
        float p = exp2_hw(s);
        p = (pkw[nk] & kb_[r]) ? 0.0f : p;
        sc[nk][r] = p;
      }
    __builtin_amdgcn_s_setprio(1);
#pragma unroll
    for (int kk = 0; kk < 2; kk++) {
      u32 a0 = cvtpk(sc[2 * kk][0], sc[2 * kk][1]);
      u32 a1 = cvtpk(sc[2 * kk][2], sc[2 * kk][3]);
      u32 b0 = cvtpk(sc[2 * kk + 1][0], sc[2 * kk + 1][1]);
      u32 b1 = cvtpk(sc[2 * kk + 1][2], sc[2 * kk + 1][3]);
      plswap32(a0, b0);
      plswap32(a1, b1);
      plswap16(a0, b0);
      plswap16(a1, b1);
      u32x4 wv = {a0, a1, b0, b1};
      bf16x8 pfrag = __builtin_bit_cast(bf16x8, wv);
      osum = MFMA16(ones_frag, pfrag, osum);
#pragma unroll
      for (int nd = 0; nd < 4; nd++) {
        bf16x8 vf = *(const bf16x8*)(bV + (nd * 16 + l15) * 64 + (c0 ^ (kk * 32)));
        octx[nd] = MFMA16(vf, pfrag, octx[nd]);
      }
    }
    __builtin_amdgcn_s_setprio(0);
  }
  const float inv = 1.0f / fmaxf(osum[0], 1e-35f);
  u16* cb = ctx + (size_t)b * 1048576 + (size_t)(q0 + l15) * 1024 + h * 64 + lg * 4;
#pragma unroll
  for (int nd = 0; nd < 4; nd++) {
    *(ushort4*)(cb + nd * 16) = make_ushort4(f2bf(octx[nd][0] * inv), f2bf(octx[nd][1] * inv),
                                             f2bf(octx[nd][2] * inv), f2bf(octx[nd][3] * inv));
  }
}

extern "C" void kernel_launch(void* const* d_in, const int* in_sizes, int n_in,
                              void* d_out, int out_size, void* d_ws, size_t ws_size,
                              hipStream_t stream) {
  (void)in_sizes; (void)n_in; (void)out_size; (void)ws_size;
  const float* Q  = (const float*)d_in[0];
  const float* K  = (const float*)d_in[1];
  const float* V  = (const float*)d_in[2];
  const float* tok = (const float*)d_in[3];
  const float* st  = (const float*)d_in[4];
  const float* df  = (const float*)d_in[5];
  const float* cf  = (const float*)d_in[6];
  const int*   msk = (const int*)d_in[8];
  const float* Wq = (const float*)d_in[9];
  const float* bq = (const float*)d_in[10];
  const float* Wk = (const float*)d_in[11];
  const float* bk = (const float*)d_in[12];
  const float* Wv = (const float*)d_in[13];
  const float* bv = (const float*)d_in[14];
  const float* Wo = (const float*)d_in[15];
  const float* bo = (const float*)d_in[16];

  char* ws = (char*)d_ws;
  const size_t MB = 1ull << 20;
  u16* Qbf = (u16*)(ws);            // 3 x 8 MB (Q,K,V bf16)
  u16* Wqb = (u16*)(ws + 24 * MB);  // 4 x 2 MB (Wq,Wk,Wv,Wo bf16)
  u8*  pkQ = (u8*)(ws + 32 * MB);   // 4 MB packed masks
  u16* Qh  = (u16*)(ws + 36 * MB);  // 3 x 8 MB (Qh,Kh,VhT)
  u16* ctx = (u16*)(ws + 60 * MB);  // 8 MB
  u16* Kbf = Qbf + 4194304;
  u16* Vbf = Qbf + 8388608;
  u16* Wkb = Wqb + 1048576;
  u16* Wvb = Wqb + 2097152;
  u16* Wob = Wqb + 3145728;

  cvt_kernel<<<4096, 256, 0, stream>>>((const float4*)Q, (const float4*)K, (const float4*)V,
                                       (const float4*)Wq, (const float4*)Wk, (const float4*)Wv, (const float4*)Wo,
                                       (ushort4*)Qbf, (ushort4*)Kbf, (ushort4*)Vbf,
                                       (ushort4*)Wqb, (ushort4*)Wkb, (ushort4*)Wvb, (ushort4*)Wob);
  gemm_qkv_pack<<<4864, 256, 0, stream>>>(Qbf, Wqb, bq, bk, bv, Qh,
                                          (const float4*)tok, (const float4*)st, (const float4*)df,
                                          (const float4*)cf, (const int4*)msk, (u32*)pkQ);
  attn_kernel<<<512, 512, 0, stream>>>(Qh, Qh + 4194304, Qh + 8388608, pkQ, ctx);
  gemm_out<<<256, 256, 0, stream>>>(ctx, Wob, bo, (float*)d_out);
}